// Round 1
// baseline (273.923 us; speedup 1.0000x reference)
//
#include <hip/hip_runtime.h>
#include <math.h>

#define NS 512
#define NF 40
#define ROWS_OUT 513
#define DTC (1.0f / 512.0f)
#define PLANE 520   // floats per component plane (512 + 8 pad)
#define PPL 260     // floats per partial component plane (256 + 4 pad)

// ws layout (floats):
//   [0..511]      w[m]            (device-computed, fp64)
//   [512..1023]   cumw2[t]        (device-computed, fp64 prefix)
//   [1024..1343]  per-forward constants, 8 per n:
//       0..2: cC = vol_scale*L[n]   3: q = nu*rho/vol_scale
//       4: cA3 = nu*sqrt(1-rho^2)   5: ca = 0.5*nu^2*DT
//       6: cm0 = mu0*DT             7: F0[n]

__global__ __launch_bounds__(64) void const_kernel(
    const float* __restrict__ F0, const float* __restrict__ alphas,
    const float* __restrict__ rhos, const float* __restrict__ nus,
    const float* __restrict__ tau, const float* __restrict__ L,
    const float* __restrict__ Lam, float* __restrict__ ws)
{
    __shared__ double wd[NS];
    __shared__ float omega0[NF];
    __shared__ float vs_s[NF];
    int n = threadIdx.x;

    // Fractional-kernel weights in fp64 on device. Depends on no inputs;
    // replaces the per-replay pageable H2D memcpy (host-staged, ~100+ us).
    {
        const double g06 = 1.4891922488128171;      // Gamma(0.6)
        const double dta = pow(512.0, 0.4);         // DT^ALPHA
        #pragma unroll
        for (int k = 0; k < 8; ++k) {
            int m = n * 8 + k;
            double wv = (pow((double)m + 1.0, 0.6) - pow((double)m, 0.6)) * (1.0 / 0.6) * dta / g06;
            wd[m] = wv;
            ws[m] = (float)wv;
        }
    }
    if (n < NF) {
        float f0 = F0[n];
        float vs = alphas[n] * sqrtf(fabsf(f0 + 0.02f));
        vs_s[n] = vs;
        omega0[n] = tau[n] * vs / (1.0f + tau[n] * f0);
    }
    __syncthreads();
    if (n == 0) {
        // serial fp64 prefix: same accumulation order as the old host loop
        double acc = 0.0;
        for (int m = 0; m < NS; ++m) { acc += wd[m] * wd[m]; ws[NS + m] = (float)acc; }
    }
    if (n < NF) {
        float s = 0.0f;
        for (int j = 0; j < NF; ++j) s += Lam[n * NF + j] * omega0[j];
        float vs = vs_s[n];
        float mu0 = -vs * s;
        float rho = rhos[n], nu = nus[n];
        float* c = ws + 1024 + n * 8;
        c[0] = vs * L[n * 3 + 0];
        c[1] = vs * L[n * 3 + 1];
        c[2] = vs * L[n * 3 + 2];
        c[3] = nu * rho / fmaxf(vs, 1e-30f);
        c[4] = nu * sqrtf(fmaxf(1.0f - rho * rho, 0.0f));
        c[5] = 0.5f * nu * nu * DTC;
        c[6] = mu0 * DTC;
        c[7] = F0[n];
    }
}

// ---- wave64 inclusive scan via DPP (pure VALU) ----
template<int CTRL, int RM>
__device__ __forceinline__ float dpp_add(float v) {
    int t = __builtin_amdgcn_update_dpp(0, __float_as_int(v), CTRL, RM, 0xf, true);
    return v + __int_as_float(t);
}
__device__ __forceinline__ float wave_iscan(float v) {
    v = dpp_add<0x111, 0xf>(v);   // row_shr:1
    v = dpp_add<0x112, 0xf>(v);   // row_shr:2
    v = dpp_add<0x114, 0xf>(v);   // row_shr:4
    v = dpp_add<0x118, 0xf>(v);   // row_shr:8
    v = dpp_add<0x142, 0xa>(v);   // row_bcast:15 -> rows 1,3
    v = dpp_add<0x143, 0xc>(v);   // row_bcast:31 -> rows 2,3
    return v;
}

__device__ __forceinline__ void fma4(float4& acc, float c, const float4& v) {
    acc.x = fmaf(c, v.x, acc.x);
    acc.y = fmaf(c, v.y, acc.y);
    acc.z = fmaf(c, v.z, acc.z);
    acc.w = fmaf(c, v.w, acc.w);
}

// one s-quad (4 steps) x 4 t's worth of FMAs into accumulators A0..A3
#define CONV_STEP(A0, A1, A2, A3, LO, HI)                                          \
    fma4(A0, HI.x, d0); fma4(A1, HI.y, d0); fma4(A2, HI.z, d0); fma4(A3, HI.w, d0);\
    fma4(A0, LO.w, d1); fma4(A1, HI.x, d1); fma4(A2, HI.y, d1); fma4(A3, HI.z, d1);\
    fma4(A0, LO.z, d2); fma4(A1, LO.w, d2); fma4(A2, HI.x, d2); fma4(A3, HI.y, d2);\
    fma4(A0, LO.y, d3); fma4(A1, LO.z, d3); fma4(A2, LO.w, d3); fma4(A3, HI.x, d3);

// 256 threads = 4 waves; 2 paths per block.
__global__ __launch_bounds__(256, 4) void path_kernel(
    const float* __restrict__ dz, const float* __restrict__ ws,
    float* __restrict__ out)
{
    __shared__ float planes[2 * 4 * PLANE];  // 16640 B: fbm4, component-major
    __shared__ float partial[2 * 4 * PPL];   //  8320 B: s-quads [0,32) partial for t>=256
    __shared__ float wp[768];                //  3072 B: wp[j] = (j<256 ? 0 : w[j-256])
    __shared__ float cw2[NS];                //  2048 B
    __shared__ float chunk[64 * 41];         // 10496 B  (total 40576 B -> 4 blocks/CU)

    int tid = threadIdx.x;
    int lane = tid & 63;
    int wv = __builtin_amdgcn_readfirstlane(tid >> 6);
    int pA = blockIdx.x * 2, pB = pA + 1;
    const float4* dzgA = (const float4*)dz + (size_t)pA * NS;
    const float4* dzgB = (const float4*)dz + (size_t)pB * NS;

    for (int i = tid; i < 768; i += 256) wp[i] = (i < 256) ? 0.0f : ws[i - 256];
    for (int i = tid; i < NS; i += 256) cw2[i] = ws[NS + i];
    __syncthreads();

    // ---- Phase B: fbm4[t] = sum_s w[t-s]*dz[s]; all 4 waves, balanced 96/96.
    // wave = {pathA-lo, pathA-hi, pathB-lo, pathB-hi}; 4 consecutive t/thread.
    // lo wave: quads [0,64) over s-quads [0,64)  +  quads [64,128) over s-quads [0,32) -> partial
    // hi wave: quads [64,128) over s-quads [32,128)
    {
        int path = wv >> 1;
        int half = wv & 1;
        const float4* dzg = path ? dzgB : dzgA;
        float* pf = planes + path * 4 * PLANE;
        float* pp = partial + path * 4 * PPL;
        const float4* wp4 = (const float4*)wp;
        float4 z4 = make_float4(0.f, 0.f, 0.f, 0.f);
        if (half == 0) {
            int i = lane;                       // t = 4i..4i+3  (t < 256)
            float4 a0 = z4, a1 = z4, a2 = z4, a3 = z4;  // own quads
            float4 b0 = z4, b1 = z4, b2 = z4, b3 = z4;  // partial for quads i+64
            #pragma unroll 2
            for (int g = 0; g < 32; ++g) {
                float4 d0 = dzg[4 * g + 0];     // wave-uniform address
                float4 d1 = dzg[4 * g + 1];
                float4 d2 = dzg[4 * g + 2];
                float4 d3 = dzg[4 * g + 3];
                float4 lo = wp4[63 + i - g], hi = wp4[64 + i - g];
                CONV_STEP(a0, a1, a2, a3, lo, hi)
                float4 lo2 = wp4[127 + i - g], hi2 = wp4[128 + i - g];
                CONV_STEP(b0, b1, b2, b3, lo2, hi2)
            }
            #pragma unroll 2
            for (int g = 32; g < 64; ++g) {
                float4 d0 = dzg[4 * g + 0];
                float4 d1 = dzg[4 * g + 1];
                float4 d2 = dzg[4 * g + 2];
                float4 d3 = dzg[4 * g + 3];
                float4 lo = wp4[63 + i - g], hi = wp4[64 + i - g];
                CONV_STEP(a0, a1, a2, a3, lo, hi)
            }
            ((float4*)(pf + 0 * PLANE))[i] = make_float4(a0.x, a1.x, a2.x, a3.x);
            ((float4*)(pf + 1 * PLANE))[i] = make_float4(a0.y, a1.y, a2.y, a3.y);
            ((float4*)(pf + 2 * PLANE))[i] = make_float4(a0.z, a1.z, a2.z, a3.z);
            ((float4*)(pf + 3 * PLANE))[i] = make_float4(a0.w, a1.w, a2.w, a3.w);
            ((float4*)(pp + 0 * PPL))[lane] = make_float4(b0.x, b1.x, b2.x, b3.x);
            ((float4*)(pp + 1 * PPL))[lane] = make_float4(b0.y, b1.y, b2.y, b3.y);
            ((float4*)(pp + 2 * PPL))[lane] = make_float4(b0.z, b1.z, b2.z, b3.z);
            ((float4*)(pp + 3 * PPL))[lane] = make_float4(b0.w, b1.w, b2.w, b3.w);
        } else {
            int i = 64 + lane;                  // t = 4i..4i+3  (t >= 256)
            float4 a0 = z4, a1 = z4, a2 = z4, a3 = z4;
            #pragma unroll 2
            for (int g = 32; g < 128; ++g) {
                float4 d0 = dzg[4 * g + 0];
                float4 d1 = dzg[4 * g + 1];
                float4 d2 = dzg[4 * g + 2];
                float4 d3 = dzg[4 * g + 3];
                float4 lo = wp4[63 + i - g], hi = wp4[64 + i - g];
                CONV_STEP(a0, a1, a2, a3, lo, hi)
            }
            ((float4*)(pf + 0 * PLANE))[i] = make_float4(a0.x, a1.x, a2.x, a3.x);
            ((float4*)(pf + 1 * PLANE))[i] = make_float4(a0.y, a1.y, a2.y, a3.y);
            ((float4*)(pf + 2 * PLANE))[i] = make_float4(a0.z, a1.z, a2.z, a3.z);
            ((float4*)(pf + 3 * PLANE))[i] = make_float4(a0.w, a1.w, a2.w, a3.w);
        }
    }

    float carryA[10], carryB[10];
    #pragma unroll
    for (int j = 0; j < 10; ++j) { carryA[j] = 0.0f; carryB[j] = 0.0f; }

    float* outA = out + (size_t)pA * (ROWS_OUT * NF);
    float* outB = out + (size_t)pB * (ROWS_OUT * NF);
    if (tid < NF) outA[tid] = ws[1024 + tid * 8 + 7];               // row 0 = F0
    if (tid >= 64 && tid < 64 + NF) outB[tid - 64] = ws[1024 + (tid - 64) * 8 + 7];

    __syncthreads();

    // ---- Phase C/D: per chunk of 64 t (lane = t): dF, DPP scan, transpose, store.
    for (int cix = 0; cix < 8; ++cix) {
        int t = cix * 64 + lane;
        float cw = cw2[t];
        #pragma unroll
        for (int path = 0; path < 2; ++path) {
            const float* pf = planes + path * 4 * PLANE;
            float fx = pf[t], fy = pf[PLANE + t], fz = pf[2 * PLANE + t], fw = pf[3 * PLANE + t];
            if (cix >= 4) {                      // add s-quads [0,32) partial (t >= 256)
                const float* pp = partial + path * 4 * PPL;
                int tt = t - 256;
                fx += pp[tt];
                fy += pp[PPL + tt];
                fz += pp[2 * PPL + tt];
                fw += pp[3 * PPL + tt];
            }
            float4 d = path ? dzgB[t] : dzgA[t];
            float* carry = path ? carryB : carryA;
            #pragma unroll
            for (int j = 0; j < 10; ++j) {
                int n = wv * 10 + j;                 // wave-uniform -> scalar loads
                const float* c = ws + 1024 + n * 8;
                float cC0 = c[0], cC1 = c[1], cC2 = c[2], q = c[3];
                float cA3 = c[4], ca = c[5], cm0 = c[6], f0 = c[7];
                float dotf = fx * cC0 + fy * cC1 + fz * cC2;
                float arg = fmaf(q, dotf, fmaf(cA3, fw, -ca * cw));
                float uv = __expf(arg);
                float dotc = d.x * cC0 + d.y * cC1 + d.z * cC2;
                float dF = uv * fmaf(cm0, uv, dotc);
                float v = wave_iscan(dF) + carry[j];
                carry[j] = __int_as_float(__builtin_amdgcn_readlane(__float_as_int(v), 63));
                chunk[lane * 41 + n] = v + f0;
            }
            __syncthreads();
            float* o = (path ? outB : outA) + NF + cix * (64 * NF);
            #pragma unroll
            for (int k = 0; k < 10; ++k) {
                int f = tid + k * 256;               // 2560 = 64 rows x 40 fwd, contiguous
                __builtin_nontemporal_store(chunk[f + f / 40], o + f);
            }
            __syncthreads();
        }
    }
}

extern "C" void kernel_launch(void* const* d_in, const int* in_sizes, int n_in,
                              void* d_out, int out_size, void* d_ws, size_t ws_size,
                              hipStream_t stream) {
    const float* dz   = (const float*)d_in[0];
    const float* F0   = (const float*)d_in[1];
    const float* alph = (const float*)d_in[2];
    const float* rhos = (const float*)d_in[3];
    const float* nus  = (const float*)d_in[4];
    const float* tau  = (const float*)d_in[5];
    const float* L    = (const float*)d_in[6];
    const float* Lam  = (const float*)d_in[7];
    float* ws = (float*)d_ws;
    float* out = (float*)d_out;

    int n_paths = in_sizes[0] / (NS * 4);

    const_kernel<<<1, 64, 0, stream>>>(F0, alph, rhos, nus, tau, L, Lam, ws);
    path_kernel<<<n_paths / 2, 256, 0, stream>>>(dz, ws, out);
}